// Round 1
// baseline (72.849 us; speedup 1.0000x reference)
//
#include <hip/hip_runtime.h>
#include <math.h>

#define NN 8192
#define HH 128
#define LRELU_ALPHA 0.2f
#define R_ROWS 152          // rows with t_i possibly nonzero in f32 (i >= 8042), padded
#define I0 (NN - R_ROWS)    // 8040
#define ISPLIT 4            // i-chunks in the w-accumulation kernel

// ---------- K1: u1 = W @ a[:H], u2 = W @ a[H:]  (each [H]) ----------
__global__ __launch_bounds__(256) void k_prep(const float* __restrict__ W,
                                              const float* __restrict__ a,
                                              float* __restrict__ u1,
                                              float* __restrict__ u2) {
    int wave = threadIdx.x >> 6, lane = threadIdx.x & 63;
    const float2* a1v = (const float2*)a;
    const float2* a2v = (const float2*)(a + HH);
    float2 av1 = a1v[lane];
    float2 av2 = a2v[lane];
    for (int k = wave; k < HH; k += 4) {
        const float2* row = (const float2*)(W + k * HH);
        float2 x = row[lane];
        float p1 = x.x * av1.x + x.y * av1.y;
        float p2 = x.x * av2.x + x.y * av2.y;
        for (int off = 32; off; off >>= 1) {
            p1 += __shfl_down(p1, off);
            p2 += __shfl_down(p2, off);
        }
        if (lane == 0) { u1[k] = p1; u2[k] = p2; }
    }
}

// ---------- K2: f1 = inp @ u1, f2 = inp @ u2  (each [N]) ----------
__global__ __launch_bounds__(256) void k_f(const float* __restrict__ inp,
                                           const float* __restrict__ u1,
                                           const float* __restrict__ u2,
                                           float* __restrict__ f1,
                                           float* __restrict__ f2) {
    int wave = threadIdx.x >> 6, lane = threadIdx.x & 63;
    int r = blockIdx.x * 4 + wave;
    const float2* row = (const float2*)(inp + (size_t)r * HH);
    float2 x  = row[lane];
    float2 av1 = ((const float2*)u1)[lane];
    float2 av2 = ((const float2*)u2)[lane];
    float p1 = x.x * av1.x + x.y * av1.y;
    float p2 = x.x * av2.x + x.y * av2.y;
    for (int off = 32; off; off >>= 1) {
        p1 += __shfl_down(p1, off);
        p2 += __shfl_down(p2, off);
    }
    if (lane == 0) { f1[r] = p1; f2[r] = p2; }
}

// ---------- K3: per-row softmax stats (max, denom) for rows I0..N-1 ----------
__global__ __launch_bounds__(256) void k_stats(const int* __restrict__ A,
                                               const float* __restrict__ f1,
                                               const float* __restrict__ f2,
                                               float* __restrict__ mrow,
                                               float* __restrict__ zrow) {
    int i = I0 + blockIdx.x;
    const int* arow = A + (size_t)i * NN;
    float f1i = f1[i];
    int tid = threadIdx.x;
    __shared__ float red_m[4];
    __shared__ float red_z[4];

    // pass 1: masked max
    float m = -INFINITY;
    for (int j = tid; j < NN; j += 256) {
        bool valid = (arow[j] > 0) || (j == i);
        if (valid) {
            float s0 = f1i + f2[j];
            float s = s0 > 0.f ? s0 : LRELU_ALPHA * s0;
            m = fmaxf(m, s);
        }
    }
    for (int off = 32; off; off >>= 1) m = fmaxf(m, __shfl_xor(m, off));
    if ((tid & 63) == 0) red_m[tid >> 6] = m;
    __syncthreads();
    m = fmaxf(fmaxf(red_m[0], red_m[1]), fmaxf(red_m[2], red_m[3]));

    // pass 2: masked sum of exp(s - m)
    float z = 0.f;
    for (int j = tid; j < NN; j += 256) {
        bool valid = (arow[j] > 0) || (j == i);
        if (valid) {
            float s0 = f1i + f2[j];
            float s = s0 > 0.f ? s0 : LRELU_ALPHA * s0;
            z += expf(s - m);
        }
    }
    for (int off = 32; off; off >>= 1) z += __shfl_xor(z, off);
    if ((tid & 63) == 0) red_z[tid >> 6] = z;
    __syncthreads();
    if (tid == 0) {
        mrow[blockIdx.x] = m;
        zrow[blockIdx.x] = red_z[0] + red_z[1] + red_z[2] + red_z[3];
    }
}

// ---------- K4: wpart[c][j] = sum over i-chunk c of (t_i/Z_i) exp(s_ij - m_i) ----------
__global__ __launch_bounds__(256) void k_wacc(const int* __restrict__ A,
                                              const float* __restrict__ f1,
                                              const float* __restrict__ f2,
                                              const float* __restrict__ mrow,
                                              const float* __restrict__ zrow,
                                              float* __restrict__ wpart) {
    int bj = blockIdx.x & 31, bc = blockIdx.x >> 5;
    int j = bj * 256 + threadIdx.x;
    float f2j = f2[j];
    float acc = 0.f;
    const int chunk = R_ROWS / ISPLIT;  // 38
    int ibeg = bc * chunk, iend = ibeg + chunk;
    for (int ii = ibeg; ii < iend; ii++) {
        int i = I0 + ii;
        // uniform-per-block scalars (broadcast loads)
        float mi = mrow[ii];
        float t  = exp2f((float)(i - NN));   // t_i = 2^-(N-i); 0.0f for early pad rows
        float ci = t / zrow[ii];
        float f1i = f1[i];
        int av = A[(size_t)i * NN + j];
        bool valid = (av > 0) || (j == i);
        if (valid) {
            float s0 = f1i + f2j;
            float s = s0 > 0.f ? s0 : LRELU_ALPHA * s0;
            acc += ci * expf(s - mi);
        }
    }
    wpart[(size_t)bc * NN + j] = acc;
}

// ---------- K5: vpart[b][k] = sum over block's j-range of w_j * inp[j][k] ----------
__global__ __launch_bounds__(256) void k_v(const float* __restrict__ inp,
                                           const float* __restrict__ wpart,
                                           float* __restrict__ vpart) {
    int k = threadIdx.x & 127, half = threadIdx.x >> 7;
    int jbase = blockIdx.x * 128;
    float acc = 0.f;
    for (int jj = half; jj < 128; jj += 2) {
        int j = jbase + jj;
        float w = wpart[j] + wpart[NN + j] + wpart[2 * NN + j] + wpart[3 * NN + j];
        acc += w * inp[(size_t)j * HH + k];
    }
    __shared__ float buf[128];
    if (half == 1) buf[k] = acc;
    __syncthreads();
    if (half == 0) vpart[blockIdx.x * HH + k] = acc + buf[k];
}

// ---------- K6: v = sum(vpart); h_t = v @ W; out = elu(h_t) ----------
__global__ __launch_bounds__(128) void k_final(const float* __restrict__ W,
                                               const float* __restrict__ vpart,
                                               float* __restrict__ out) {
    __shared__ float v[128];
    int e = threadIdx.x;
    float s = 0.f;
    for (int b = 0; b < 64; b++) s += vpart[b * HH + e];
    v[e] = s;
    __syncthreads();
    float ht = 0.f;
    for (int k = 0; k < HH; k++) ht += v[k] * W[k * HH + e];
    out[e] = ht > 0.f ? ht : expm1f(ht);
}

extern "C" void kernel_launch(void* const* d_in, const int* in_sizes, int n_in,
                              void* d_out, int out_size, void* d_ws, size_t ws_size,
                              hipStream_t stream) {
    const float* inp = (const float*)d_in[0];   // [8192,128] f32
    const int*   A   = (const int*)d_in[1];     // [8192,8192] i32
    const float* W   = (const float*)d_in[2];   // [128,128] f32
    const float* a   = (const float*)d_in[3];   // [256,1] f32
    float* out = (float*)d_out;                 // [128] f32
    float* ws = (float*)d_ws;

    // workspace layout (floats)
    float* u1    = ws;               // 128
    float* u2    = ws + 128;         // 128
    float* f1    = ws + 256;         // 8192
    float* f2    = ws + 8448;        // 8192
    float* mrow  = ws + 16640;       // 160 (152 used)
    float* zrow  = ws + 16800;       // 160
    float* wpart = ws + 16960;       // ISPLIT * 8192 = 32768
    float* vpart = ws + 49728;       // 64 * 128 = 8192
    // total: 57920 floats = ~232 KB

    k_prep <<<1,            256, 0, stream>>>(W, a, u1, u2);
    k_f    <<<NN / 4,       256, 0, stream>>>(inp, u1, u2, f1, f2);
    k_stats<<<R_ROWS,       256, 0, stream>>>(A, f1, f2, mrow, zrow);
    k_wacc <<<32 * ISPLIT,  256, 0, stream>>>(A, f1, f2, mrow, zrow, wpart);
    k_v    <<<NN / 128,     256, 0, stream>>>(inp, wpart, vpart);
    k_final<<<1,            128, 0, stream>>>(W, vpart, out);
}